// Round 4
// baseline (937.475 us; speedup 1.0000x reference)
//
#include <hip/hip_runtime.h>

// DGMNet fused kernel for MI355X (gfx950) — round 4.
// R3 post-mortem: per-wave live state ~238 VGPRs; allocator targeted the
// 128-reg / 4-waves-per-EU occupancy step and spilled ~96 regs/lane
// (WRITE_SIZE 394MB of scratch, FETCH 629MB incl. fills). R4: force the
// allocation target with amdgpu_waves_per_eu(2,2) so RA uses the full
// 256-VGPR budget (2 waves/EU, 1 block/CU) with zero spill. Structure
// otherwise identical to R3: 512 threads, 8 waves x 1 n-tile, weights
// persistent in VGPR B-fragments, activations in LDS A-fragment order.

typedef __attribute__((ext_vector_type(8))) short bf16x8;
typedef __attribute__((ext_vector_type(4))) float f32x4;
typedef __attribute__((ext_vector_type(4))) unsigned int u32x4;
typedef __attribute__((ext_vector_type(2))) unsigned int u32x2;

#define HID 128
#define XD 100
#define BROWS 128
#define NMAT 9
#define MATS 16384   // ushorts per 128x128 matrix

// ---------- bf16 helpers (RNE) ----------
__device__ __forceinline__ unsigned short f2bf(float f) {
    unsigned u = __float_as_uint(f);
    return (unsigned short)((u + 0x7FFFu + ((u >> 16) & 1u)) >> 16);
}
__device__ __forceinline__ unsigned pack2(float lo, float hi) {
    unsigned ul = __float_as_uint(lo), uh = __float_as_uint(hi);
    unsigned bl = (ul + 0x7FFFu + ((ul >> 16) & 1u)) >> 16;
    unsigned bh = (uh + 0x7FFFu + ((uh >> 16) & 1u)) & 0xFFFF0000u;
    return bl | bh;
}
__device__ __forceinline__ float bf_lo(unsigned p) { return __uint_as_float(p << 16); }
__device__ __forceinline__ float bf_hi(unsigned p) { return __uint_as_float(p & 0xFFFF0000u); }

__device__ __forceinline__ float fast_tanh(float x) {
    float e = __expf(2.0f * x);
    return 1.0f - 2.0f * __builtin_amdgcn_rcpf(e + 1.0f);
}
__device__ __forceinline__ float one_m_tanh(float x) {   // 1 - tanh(x)
    float e = __expf(2.0f * x);
    return 2.0f * __builtin_amdgcn_rcpf(e + 1.0f);
}

// ---------- prep: fp32 [K][128] -> bf16 fragment order ----------
__global__ void prep_kernel(const float* __restrict__ Sw, const float* __restrict__ Uz,
                            const float* __restrict__ Ug, const float* __restrict__ Ur,
                            const float* __restrict__ Uh, const float* __restrict__ Wsz,
                            const float* __restrict__ Wsg, const float* __restrict__ Wsr,
                            const float* __restrict__ Wsh, unsigned short* __restrict__ out) {
    int g = blockIdx.x * blockDim.x + threadIdx.x;
    if (g >= NMAT * 2048) return;
    int m = g / 2048, r = g % 2048;
    int lane = r & 63, nt = (r >> 6) & 7, ks = r >> 9;
    const float* src; int kmax;
    switch (m) {
        case 0: src = Sw;  kmax = 101; break;
        case 1: src = Uz;  kmax = 101; break;
        case 2: src = Ug;  kmax = 101; break;
        case 3: src = Ur;  kmax = 101; break;
        case 4: src = Uh;  kmax = 101; break;
        case 5: src = Wsz; kmax = 128; break;
        case 6: src = Wsg; kmax = 128; break;
        case 7: src = Wsr; kmax = 128; break;
        default: src = Wsh; kmax = 128; break;
    }
    int n = nt * 16 + (lane & 15);
    int k0 = ks * 32 + (lane >> 4) * 8;
    __attribute__((aligned(16))) unsigned short tmp[8];
    #pragma unroll
    for (int b = 0; b < 8; ++b) {
        int k = k0 + b;
        float v = (k < kmax) ? src[k * HID + n] : 0.0f;
        tmp[b] = f2bf(v);
    }
    *(u32x4*)(out + (size_t)m * MATS + (size_t)r * 8) = *(const u32x4*)tmp;
}

// ---------- GEMM: A (LDS, frag order) x B (regs, 1 n-tile) ----------
__device__ __forceinline__ void gemm128(const unsigned short* __restrict__ A,
                                        const bf16x8 (&B)[4], int lane,
                                        f32x4 (&acc)[8]) {
    #pragma unroll
    for (int ks = 0; ks < 4; ++ks) {
        #pragma unroll
        for (int mt = 0; mt < 8; ++mt) {
            bf16x8 a = *(const bf16x8*)(A + mt * 2048 + ks * 512 + lane * 8);
            acc[mt] = __builtin_amdgcn_mfma_f32_16x16x32_bf16(a, B[ks], acc[mt], 0, 0, 0);
        }
    }
}

__device__ __forceinline__ void zeroacc(f32x4 (&acc)[8]) {
    #pragma unroll
    for (int mt = 0; mt < 8; ++mt)
        acc[mt] = (f32x4){0.f, 0.f, 0.f, 0.f};
}

__device__ __forceinline__ void loadB(const unsigned short* __restrict__ wbuf, int mat,
                                      int nt, int lane, bf16x8 (&B)[4]) {
    #pragma unroll
    for (int ks = 0; ks < 4; ++ks)
        B[ks] = *(const bf16x8*)(wbuf + (size_t)mat * MATS +
                                 ((size_t)((ks * 8 + nt) * 64 + lane)) * 8);
}

// ---------- main ----------
__global__ __launch_bounds__(512)
__attribute__((amdgpu_waves_per_eu(2, 2)))
void dgm_main(const float* __restrict__ x, const float* __restrict__ tptr,
              const unsigned short* __restrict__ wbuf,
              const float* __restrict__ Sw_b, const float* __restrict__ Uz_b,
              const float* __restrict__ Ug_b, const float* __restrict__ Ur_b,
              const float* __restrict__ Uh_b,
              const float* __restrict__ Wsz_b, const float* __restrict__ Wsg_b,
              const float* __restrict__ Wsr_b, const float* __restrict__ Wsh_b,
              const float* __restrict__ Wf_w, const float* __restrict__ Wf_b,
              const int* __restrict__ nlayers, float* __restrict__ y) {
    __shared__ unsigned short xtb[BROWS * HID];  // A-frag order: xt, later S*R. 32KB
    __shared__ unsigned short sb[BROWS * HID];   // A-frag order: S.           32KB

    const int tid = threadIdx.x;
    const int wv = tid >> 6, lane = tid & 63;
    const int quad = lane >> 4, l15 = lane & 15;
    const int blk = blockIdx.x;
    const int lcount = nlayers[0] - 1;
    const int nt = wv;                       // one 16-col n-tile per wave

    const int col = nt * 16 + l15;
    const int sc = (col >> 5) * 512 + ((col >> 3) & 3) * 128 + (col & 7) + quad * 32;

    // ---- zero the k>=96 pad frags of xtb (frag ks==3), then fill xt ----
    for (int i = tid; i < 2048; i += 512) {
        int mt = i >> 8;
        ((unsigned*)xtb)[(mt * 4 + 3) * 256 + (i & 255)] = 0u;
    }
    __syncthreads();

    {
        const float* xsrc = x + (size_t)blk * BROWS * XD;
        for (int i = tid; i < BROWS * (XD / 4); i += 512) {     // 3200 float4s
            int row = i / 25, c4 = i % 25, k0 = c4 * 4;
            f32x4 v = *(const f32x4*)(xsrc + row * XD + k0);
            int idx = (row >> 4) * 2048 + (k0 >> 5) * 512 + ((k0 >> 3) & 3) * 128 +
                      (row & 15) * 8 + (k0 & 7);
            *(u32x2*)(xtb + idx) = (u32x2){pack2(v[0], v[1]), pack2(v[2], v[3])};
        }
        if (tid < BROWS) {                                      // t column, k=100
            int idx = (tid >> 4) * 2048 + 3 * 512 + (tid & 15) * 8 + 4;
            xtb[idx] = f2bf(tptr[(size_t)blk * BROWS + tid]);
        }
    }
    __syncthreads();

    f32x4 acc[8];
    unsigned sreg[8][2];      // packed bf16 S at C-layout
    unsigned u[4][8][2];      // packed bf16: 0 uz, 1 ug, 2 ur, 3 uh
    bf16x8 Bcur[4], Bnxt[4];

    // ---- projection phase: Sw, then Uz/Ug/Ur/Uh ----
    loadB(wbuf, 0, nt, lane, Bcur);
    {
        float bv = Sw_b[col];
        loadB(wbuf, 1, nt, lane, Bnxt);   // prefetch Uz
        zeroacc(acc);
        gemm128(xtb, Bcur, lane, acc);
        #pragma unroll
        for (int mt = 0; mt < 8; ++mt) {
            float s0 = fast_tanh(acc[mt][0] + bv);
            float s1 = fast_tanh(acc[mt][1] + bv);
            float s2 = fast_tanh(acc[mt][2] + bv);
            float s3 = fast_tanh(acc[mt][3] + bv);
            unsigned p01 = pack2(s0, s1), p23 = pack2(s2, s3);
            sreg[mt][0] = p01; sreg[mt][1] = p23;
            int base = mt * 2048 + sc;
            sb[base + 0]  = (unsigned short)p01;
            sb[base + 8]  = (unsigned short)(p01 >> 16);
            sb[base + 16] = (unsigned short)p23;
            sb[base + 24] = (unsigned short)(p23 >> 16);
        }
    }
    {
        const float* ubias[4] = {Uz_b, Ug_b, Ur_b, Uh_b};
        #pragma unroll
        for (int mi = 0; mi < 4; ++mi) {
            #pragma unroll
            for (int ks = 0; ks < 4; ++ks)
                Bcur[ks] = Bnxt[ks];
            if (mi < 3) loadB(wbuf, mi + 2, nt, lane, Bnxt);
            float bv = ubias[mi][col];
            zeroacc(acc);
            gemm128(xtb, Bcur, lane, acc);
            #pragma unroll
            for (int mt = 0; mt < 8; ++mt) {
                u[mi][mt][0] = pack2(acc[mt][0] + bv, acc[mt][1] + bv);
                u[mi][mt][1] = pack2(acc[mt][2] + bv, acc[mt][3] + bv);
            }
        }
    }
    __syncthreads();   // S1 visible to all waves

    // ---- persistent layer weights (B-fragments, this wave's n-tile) ----
    bf16x8 Wz[4], Wg[4], Wr[4], Wh[4];
    loadB(wbuf, 5, nt, lane, Wz);
    loadB(wbuf, 6, nt, lane, Wg);
    loadB(wbuf, 7, nt, lane, Wr);
    loadB(wbuf, 8, nt, lane, Wh);

    const float brv = Wsr_b[col];
    const float bzv = Wsz_b[col];
    const float bgv = Wsg_b[col];
    const float bhv = Wsh_b[col];

    unsigned tp[8][2];   // packed Z*S
    unsigned gp[8][2];   // packed (1-G)

    // ---- recurrent layers: R -> Z -> G -> H ----
    for (int l = 0; l < lcount; ++l) {
        // R = tanh(ur + S@Wsr + br); write S*R into xtb
        zeroacc(acc);
        gemm128(sb, Wr, lane, acc);
        #pragma unroll
        for (int mt = 0; mt < 8; ++mt) {
            float r0 = fast_tanh(acc[mt][0] + bf_lo(u[2][mt][0]) + brv);
            float r1 = fast_tanh(acc[mt][1] + bf_hi(u[2][mt][0]) + brv);
            float r2 = fast_tanh(acc[mt][2] + bf_lo(u[2][mt][1]) + brv);
            float r3 = fast_tanh(acc[mt][3] + bf_hi(u[2][mt][1]) + brv);
            unsigned q01 = pack2(bf_lo(sreg[mt][0]) * r0, bf_hi(sreg[mt][0]) * r1);
            unsigned q23 = pack2(bf_lo(sreg[mt][1]) * r2, bf_hi(sreg[mt][1]) * r3);
            int base = mt * 2048 + sc;
            xtb[base + 0]  = (unsigned short)q01;
            xtb[base + 8]  = (unsigned short)(q01 >> 16);
            xtb[base + 16] = (unsigned short)q23;
            xtb[base + 24] = (unsigned short)(q23 >> 16);
        }
        __syncthreads();   // S*R visible

        // Z = tanh(uz + S@Wsz + bz); tp = Z*S
        zeroacc(acc);
        gemm128(sb, Wz, lane, acc);
        #pragma unroll
        for (int mt = 0; mt < 8; ++mt) {
            float z0 = fast_tanh(acc[mt][0] + bf_lo(u[0][mt][0]) + bzv);
            float z1 = fast_tanh(acc[mt][1] + bf_hi(u[0][mt][0]) + bzv);
            float z2 = fast_tanh(acc[mt][2] + bf_lo(u[0][mt][1]) + bzv);
            float z3 = fast_tanh(acc[mt][3] + bf_hi(u[0][mt][1]) + bzv);
            tp[mt][0] = pack2(z0 * bf_lo(sreg[mt][0]), z1 * bf_hi(sreg[mt][0]));
            tp[mt][1] = pack2(z2 * bf_lo(sreg[mt][1]), z3 * bf_hi(sreg[mt][1]));
        }

        // 1-G
        zeroacc(acc);
        gemm128(sb, Wg, lane, acc);
        #pragma unroll
        for (int mt = 0; mt < 8; ++mt) {
            float g0 = one_m_tanh(acc[mt][0] + bf_lo(u[1][mt][0]) + bgv);
            float g1 = one_m_tanh(acc[mt][1] + bf_hi(u[1][mt][0]) + bgv);
            float g2 = one_m_tanh(acc[mt][2] + bf_lo(u[1][mt][1]) + bgv);
            float g3 = one_m_tanh(acc[mt][3] + bf_hi(u[1][mt][1]) + bgv);
            gp[mt][0] = pack2(g0, g1);
            gp[mt][1] = pack2(g2, g3);
        }

        // H = uh + (S*R)@Wsh + bh ; out = (1-G)*H + Z*S
        zeroacc(acc);
        gemm128(xtb, Wh, lane, acc);
        __syncthreads();   // all waves done reading sb/xtb for this layer
        bool lastl = (l == lcount - 1);
        #pragma unroll
        for (int mt = 0; mt < 8; ++mt) {
            float h0 = acc[mt][0] + bf_lo(u[3][mt][0]) + bhv;
            float h1 = acc[mt][1] + bf_hi(u[3][mt][0]) + bhv;
            float h2 = acc[mt][2] + bf_lo(u[3][mt][1]) + bhv;
            float h3 = acc[mt][3] + bf_hi(u[3][mt][1]) + bhv;
            float o0 = bf_lo(gp[mt][0]) * h0 + bf_lo(tp[mt][0]);
            float o1 = bf_hi(gp[mt][0]) * h1 + bf_hi(tp[mt][0]);
            float o2 = bf_lo(gp[mt][1]) * h2 + bf_lo(tp[mt][1]);
            float o3 = bf_hi(gp[mt][1]) * h3 + bf_hi(tp[mt][1]);
            acc[mt] = (f32x4){o0, o1, o2, o3};   // keep for final GEMV
            unsigned p01 = pack2(o0, o1), p23 = pack2(o2, o3);
            sreg[mt][0] = p01; sreg[mt][1] = p23;
            if (!lastl) {
                int base = mt * 2048 + sc;
                sb[base + 0]  = (unsigned short)p01;
                sb[base + 8]  = (unsigned short)(p01 >> 16);
                sb[base + 16] = (unsigned short)p23;
                sb[base + 24] = (unsigned short)(p23 >> 16);
            }
        }
        if (!lastl) __syncthreads();   // new S visible for next layer
    }

    // ---- final: y = out @ Wf + Wf_b ----
    float* yp = (float*)xtb;   // safe: barrier after H-gemm ended all xtb reads
    float wfv = Wf_w[col];
    #pragma unroll
    for (int mt = 0; mt < 8; ++mt)
        #pragma unroll
        for (int e = 0; e < 4; ++e) {
            float p = acc[mt][e] * wfv;
            p += __shfl_xor(p, 1);
            p += __shfl_xor(p, 2);
            p += __shfl_xor(p, 4);
            p += __shfl_xor(p, 8);
            if (l15 == 0) yp[(mt * 16 + quad * 4 + e) * 8 + wv] = p;
        }
    __syncthreads();
    if (tid < BROWS) {
        const float* r8 = yp + tid * 8;
        float r = ((r8[0] + r8[1]) + (r8[2] + r8[3])) +
                  ((r8[4] + r8[5]) + (r8[6] + r8[7])) + Wf_b[0];
        y[(size_t)blk * BROWS + tid] = r;
    }
}

extern "C" void kernel_launch(void* const* d_in, const int* in_sizes, int n_in,
                              void* d_out, int out_size, void* d_ws, size_t ws_size,
                              hipStream_t stream) {
    const float* x     = (const float*)d_in[0];
    const float* t     = (const float*)d_in[1];
    const float* Sw_w  = (const float*)d_in[2];
    const float* Sw_b  = (const float*)d_in[3];
    const float* Uz_w  = (const float*)d_in[4];
    const float* Uz_b  = (const float*)d_in[5];
    const float* Wsz_w = (const float*)d_in[6];
    const float* Wsz_b = (const float*)d_in[7];
    const float* Ug_w  = (const float*)d_in[8];
    const float* Ug_b  = (const float*)d_in[9];
    const float* Wsg_w = (const float*)d_in[10];
    const float* Wsg_b = (const float*)d_in[11];
    const float* Ur_w  = (const float*)d_in[12];
    const float* Ur_b  = (const float*)d_in[13];
    const float* Wsr_w = (const float*)d_in[14];
    const float* Wsr_b = (const float*)d_in[15];
    const float* Uh_w  = (const float*)d_in[16];
    const float* Uh_b  = (const float*)d_in[17];
    const float* Wsh_w = (const float*)d_in[18];
    const float* Wsh_b = (const float*)d_in[19];
    const float* Wf_w  = (const float*)d_in[20];
    const float* Wf_b  = (const float*)d_in[21];
    const int*   nl    = (const int*)d_in[22];

    unsigned short* wbuf = (unsigned short*)d_ws;
    float* y = (float*)d_out;
    const int B = in_sizes[0] / XD;

    prep_kernel<<<dim3((NMAT * 2048 + 255) / 256), dim3(256), 0, stream>>>(
        Sw_w, Uz_w, Ug_w, Ur_w, Uh_w, Wsz_w, Wsg_w, Wsr_w, Wsh_w, wbuf);

    dgm_main<<<dim3(B / BROWS), dim3(512), 0, stream>>>(
        x, t, wbuf, Sw_b, Uz_b, Ug_b, Ur_b, Uh_b,
        Wsz_b, Wsg_b, Wsr_b, Wsh_b, Wf_w, Wf_b, nl, y);
}

// Round 5
// 436.364 us; speedup vs baseline: 2.1484x; 2.1484x over previous
//
#include <hip/hip_runtime.h>

// DGMNet fused kernel for MI355X (gfx950) — round 5.
// R2-R4 evidence: the register allocator targets the LDS-limited occupancy
// tier (R2: 64KB LDS/256thr -> 2 waves/EU -> 256 regs; R3/R4: 64KB/512thr ->
// 4 waves/EU -> 128 regs) and spills the excess. waves_per_eu attr is ignored.
// R5: make live state fit 128 regs and pin the LDS cap to that tier.
//   - BROWS=32 per block, 512 threads, 8 waves x 1 n-tile x 2 row-tiles.
//   - u-projections moved from regs (64) to lane-private LDS (32KB,
//     one conflict-free ds_read_b128 per gate epilogue).
//   - Real LDS 48KB, padded to 56KB -> LDS cap 2 blocks/CU = 4 waves/EU
//     -> RA budget 128 regs >= ~110 live. Occupancy 2 blocks/CU.
// Weights persist in VGPR B-fragments; activations in LDS A-frag order.

typedef __attribute__((ext_vector_type(8))) short bf16x8;
typedef __attribute__((ext_vector_type(4))) float f32x4;
typedef __attribute__((ext_vector_type(4))) unsigned int u32x4;
typedef __attribute__((ext_vector_type(2))) unsigned int u32x2;

#define HID 128
#define XD 100
#define BROWS 32
#define NMAT 9
#define MATS 16384   // ushorts per 128x128 matrix

// ---------- bf16 helpers (RNE) ----------
__device__ __forceinline__ unsigned short f2bf(float f) {
    unsigned u = __float_as_uint(f);
    return (unsigned short)((u + 0x7FFFu + ((u >> 16) & 1u)) >> 16);
}
__device__ __forceinline__ unsigned pack2(float lo, float hi) {
    unsigned ul = __float_as_uint(lo), uh = __float_as_uint(hi);
    unsigned bl = (ul + 0x7FFFu + ((ul >> 16) & 1u)) >> 16;
    unsigned bh = (uh + 0x7FFFu + ((uh >> 16) & 1u)) & 0xFFFF0000u;
    return bl | bh;
}
__device__ __forceinline__ float bf_lo(unsigned p) { return __uint_as_float(p << 16); }
__device__ __forceinline__ float bf_hi(unsigned p) { return __uint_as_float(p & 0xFFFF0000u); }

__device__ __forceinline__ float fast_tanh(float x) {
    float e = __expf(2.0f * x);
    return 1.0f - 2.0f * __builtin_amdgcn_rcpf(e + 1.0f);
}
__device__ __forceinline__ float one_m_tanh(float x) {   // 1 - tanh(x)
    float e = __expf(2.0f * x);
    return 2.0f * __builtin_amdgcn_rcpf(e + 1.0f);
}

// ---------- prep: fp32 [K][128] -> bf16 fragment order ----------
// mats: 0 Sw 1 Uz 2 Ug 3 Ur 4 Uh (K=101, pad to 128) | 5 Wsz 6 Wsg 7 Wsr 8 Wsh
// layout: ((ks*8 + nt)*64 + lane)*8 + b <-> W[k=ks*32+(lane>>4)*8+b][n=nt*16+(lane&15)]
__global__ void prep_kernel(const float* __restrict__ Sw, const float* __restrict__ Uz,
                            const float* __restrict__ Ug, const float* __restrict__ Ur,
                            const float* __restrict__ Uh, const float* __restrict__ Wsz,
                            const float* __restrict__ Wsg, const float* __restrict__ Wsr,
                            const float* __restrict__ Wsh, unsigned short* __restrict__ out) {
    int g = blockIdx.x * blockDim.x + threadIdx.x;
    if (g >= NMAT * 2048) return;
    int m = g / 2048, r = g % 2048;
    int lane = r & 63, nt = (r >> 6) & 7, ks = r >> 9;
    const float* src; int kmax;
    switch (m) {
        case 0: src = Sw;  kmax = 101; break;
        case 1: src = Uz;  kmax = 101; break;
        case 2: src = Ug;  kmax = 101; break;
        case 3: src = Ur;  kmax = 101; break;
        case 4: src = Uh;  kmax = 101; break;
        case 5: src = Wsz; kmax = 128; break;
        case 6: src = Wsg; kmax = 128; break;
        case 7: src = Wsr; kmax = 128; break;
        default: src = Wsh; kmax = 128; break;
    }
    int n = nt * 16 + (lane & 15);
    int k0 = ks * 32 + (lane >> 4) * 8;
    __attribute__((aligned(16))) unsigned short tmp[8];
    #pragma unroll
    for (int b = 0; b < 8; ++b) {
        int k = k0 + b;
        float v = (k < kmax) ? src[k * HID + n] : 0.0f;
        tmp[b] = f2bf(v);
    }
    *(u32x4*)(out + (size_t)m * MATS + (size_t)r * 8) = *(const u32x4*)tmp;
}

// ---------- GEMM: A (LDS, frag order, 32 rows x 128 k) x B (regs, 1 n-tile) ----------
__device__ __forceinline__ void gemm32(const unsigned short* __restrict__ A,
                                       const bf16x8 (&B)[4], int lane,
                                       f32x4 (&acc)[2]) {
    #pragma unroll
    for (int ks = 0; ks < 4; ++ks) {
        #pragma unroll
        for (int mt = 0; mt < 2; ++mt) {
            bf16x8 a = *(const bf16x8*)(A + mt * 2048 + ks * 512 + lane * 8);
            acc[mt] = __builtin_amdgcn_mfma_f32_16x16x32_bf16(a, B[ks], acc[mt], 0, 0, 0);
        }
    }
}

__device__ __forceinline__ void zeroacc(f32x4 (&acc)[2]) {
    acc[0] = (f32x4){0.f, 0.f, 0.f, 0.f};
    acc[1] = (f32x4){0.f, 0.f, 0.f, 0.f};
}

__device__ __forceinline__ void loadB(const unsigned short* __restrict__ wbuf, int mat,
                                      int nt, int lane, bf16x8 (&B)[4]) {
    #pragma unroll
    for (int ks = 0; ks < 4; ++ks)
        B[ks] = *(const bf16x8*)(wbuf + (size_t)mat * MATS +
                                 ((size_t)((ks * 8 + nt) * 64 + lane)) * 8);
}

// ---------- main ----------
__global__ __launch_bounds__(512, 4)
void dgm_main(const float* __restrict__ x, const float* __restrict__ tptr,
              const unsigned short* __restrict__ wbuf,
              const float* __restrict__ Sw_b, const float* __restrict__ Uz_b,
              const float* __restrict__ Ug_b, const float* __restrict__ Ur_b,
              const float* __restrict__ Uh_b,
              const float* __restrict__ Wsz_b, const float* __restrict__ Wsg_b,
              const float* __restrict__ Wsr_b, const float* __restrict__ Wsh_b,
              const float* __restrict__ Wf_w, const float* __restrict__ Wf_b,
              const int* __restrict__ nlayers, float* __restrict__ y) {
    __shared__ unsigned short xtb[2 * 2048];    // 8KB: xt, later S*R (A-frag order)
    __shared__ unsigned short sb[2 * 2048];     // 8KB: S (A-frag order)
    __shared__ unsigned short ub[4 * 4096];     // 32KB: u projections, lane-private
    __shared__ unsigned short ldspad[4096];     // 8KB pad -> 56KB total: pins LDS
                                                // cap at 2 blocks/CU = 4 waves/EU
                                                // so RA budget = 128 regs (R2-R4)

    const int tid = threadIdx.x;
    const int wv = tid >> 6, lane = tid & 63;
    const int quad = lane >> 4, l15 = lane & 15;
    const int blk = blockIdx.x;
    const int lcount = nlayers[0] - 1;
    const int nt = wv;                       // one 16-col n-tile per wave

    if (lcount > 1000000) ldspad[tid] = 0;   // never true; keeps pad allocated

    const int col = nt * 16 + l15;
    const int sc = (col >> 5) * 512 + ((col >> 3) & 3) * 128 + (col & 7) + quad * 32;

    // ---- zero the k>=96 pad frags of xtb (frag ks==3), then fill xt ----
    {
        int mt = tid >> 8;
        ((unsigned*)xtb)[mt * 1024 + 768 + (tid & 255)] = 0u;
    }
    __syncthreads();

    {
        const float* xsrc = x + (size_t)blk * BROWS * XD;
        for (int i = tid; i < BROWS * (XD / 4); i += 512) {     // 800 float4s
            int row = i / 25, c4 = i % 25, k0 = c4 * 4;
            f32x4 v = *(const f32x4*)(xsrc + row * XD + k0);
            int idx = (row >> 4) * 2048 + (k0 >> 5) * 512 + ((k0 >> 3) & 3) * 128 +
                      (row & 15) * 8 + (k0 & 7);
            *(u32x2*)(xtb + idx) = (u32x2){pack2(v[0], v[1]), pack2(v[2], v[3])};
        }
        if (tid < BROWS) {                                      // t column, k=100
            int idx = (tid >> 4) * 2048 + 3 * 512 + (tid & 15) * 8 + 4;
            xtb[idx] = f2bf(tptr[(size_t)blk * BROWS + tid]);
        }
    }
    __syncthreads();

    f32x4 acc[2];
    unsigned sreg[2][2];      // packed bf16 S at C-layout
    bf16x8 Bcur[4], Bnxt[4];

    // ---- projection phase: Sw, then Uz/Ug/Ur/Uh (u -> lane-private LDS) ----
    loadB(wbuf, 0, nt, lane, Bcur);
    {
        float bv = Sw_b[col];
        loadB(wbuf, 1, nt, lane, Bnxt);   // prefetch Uz
        zeroacc(acc);
        gemm32(xtb, Bcur, lane, acc);
        #pragma unroll
        for (int mt = 0; mt < 2; ++mt) {
            float s0 = fast_tanh(acc[mt][0] + bv);
            float s1 = fast_tanh(acc[mt][1] + bv);
            float s2 = fast_tanh(acc[mt][2] + bv);
            float s3 = fast_tanh(acc[mt][3] + bv);
            unsigned p01 = pack2(s0, s1), p23 = pack2(s2, s3);
            sreg[mt][0] = p01; sreg[mt][1] = p23;
            int base = mt * 2048 + sc;
            sb[base + 0]  = (unsigned short)p01;
            sb[base + 8]  = (unsigned short)(p01 >> 16);
            sb[base + 16] = (unsigned short)p23;
            sb[base + 24] = (unsigned short)(p23 >> 16);
        }
    }
    {
        const float* ubias[4] = {Uz_b, Ug_b, Ur_b, Uh_b};
        #pragma unroll
        for (int mi = 0; mi < 4; ++mi) {
            #pragma unroll
            for (int ks = 0; ks < 4; ++ks)
                Bcur[ks] = Bnxt[ks];
            if (mi < 3) loadB(wbuf, mi + 2, nt, lane, Bnxt);
            float bv = ubias[mi][col];
            zeroacc(acc);
            gemm32(xtb, Bcur, lane, acc);
            u32x4 uw;
            uw[0] = pack2(acc[0][0] + bv, acc[0][1] + bv);
            uw[1] = pack2(acc[0][2] + bv, acc[0][3] + bv);
            uw[2] = pack2(acc[1][0] + bv, acc[1][1] + bv);
            uw[3] = pack2(acc[1][2] + bv, acc[1][3] + bv);
            *(u32x4*)(ub + mi * 4096 + tid * 8) = uw;   // lane-private, no barrier
        }
    }
    __syncthreads();   // S1 visible to all waves

    // ---- persistent layer weights (B-fragments, this wave's n-tile) ----
    bf16x8 Wz[4], Wg[4], Wr[4], Wh[4];
    loadB(wbuf, 5, nt, lane, Wz);
    loadB(wbuf, 6, nt, lane, Wg);
    loadB(wbuf, 7, nt, lane, Wr);
    loadB(wbuf, 8, nt, lane, Wh);

    const float brv = Wsr_b[col];
    const float bzv = Wsz_b[col];
    const float bgv = Wsg_b[col];
    const float bhv = Wsh_b[col];

    unsigned tp[2][2];   // packed Z*S
    unsigned gp[2][2];   // packed (1-G)

    // ---- recurrent layers: R -> Z -> G -> H ----
    for (int l = 0; l < lcount; ++l) {
        // R = tanh(ur + S@Wsr + br); write S*R into xtb
        zeroacc(acc);
        gemm32(sb, Wr, lane, acc);
        {
            u32x4 uq = *(const u32x4*)(ub + 2 * 4096 + tid * 8);   // ur
            #pragma unroll
            for (int mt = 0; mt < 2; ++mt) {
                float r0 = fast_tanh(acc[mt][0] + bf_lo(uq[mt * 2]) + brv);
                float r1 = fast_tanh(acc[mt][1] + bf_hi(uq[mt * 2]) + brv);
                float r2 = fast_tanh(acc[mt][2] + bf_lo(uq[mt * 2 + 1]) + brv);
                float r3 = fast_tanh(acc[mt][3] + bf_hi(uq[mt * 2 + 1]) + brv);
                unsigned q01 = pack2(bf_lo(sreg[mt][0]) * r0, bf_hi(sreg[mt][0]) * r1);
                unsigned q23 = pack2(bf_lo(sreg[mt][1]) * r2, bf_hi(sreg[mt][1]) * r3);
                int base = mt * 2048 + sc;
                xtb[base + 0]  = (unsigned short)q01;
                xtb[base + 8]  = (unsigned short)(q01 >> 16);
                xtb[base + 16] = (unsigned short)q23;
                xtb[base + 24] = (unsigned short)(q23 >> 16);
            }
        }
        __syncthreads();   // S*R visible

        // Z = tanh(uz + S@Wsz + bz); tp = Z*S
        zeroacc(acc);
        gemm32(sb, Wz, lane, acc);
        {
            u32x4 uq = *(const u32x4*)(ub + 0 * 4096 + tid * 8);   // uz
            #pragma unroll
            for (int mt = 0; mt < 2; ++mt) {
                float z0 = fast_tanh(acc[mt][0] + bf_lo(uq[mt * 2]) + bzv);
                float z1 = fast_tanh(acc[mt][1] + bf_hi(uq[mt * 2]) + bzv);
                float z2 = fast_tanh(acc[mt][2] + bf_lo(uq[mt * 2 + 1]) + bzv);
                float z3 = fast_tanh(acc[mt][3] + bf_hi(uq[mt * 2 + 1]) + bzv);
                tp[mt][0] = pack2(z0 * bf_lo(sreg[mt][0]), z1 * bf_hi(sreg[mt][0]));
                tp[mt][1] = pack2(z2 * bf_lo(sreg[mt][1]), z3 * bf_hi(sreg[mt][1]));
            }
        }

        // 1-G = 2/(exp(2*(ug + S@Wsg + bg))+1)
        zeroacc(acc);
        gemm32(sb, Wg, lane, acc);
        {
            u32x4 uq = *(const u32x4*)(ub + 1 * 4096 + tid * 8);   // ug
            #pragma unroll
            for (int mt = 0; mt < 2; ++mt) {
                float g0 = one_m_tanh(acc[mt][0] + bf_lo(uq[mt * 2]) + bgv);
                float g1 = one_m_tanh(acc[mt][1] + bf_hi(uq[mt * 2]) + bgv);
                float g2 = one_m_tanh(acc[mt][2] + bf_lo(uq[mt * 2 + 1]) + bgv);
                float g3 = one_m_tanh(acc[mt][3] + bf_hi(uq[mt * 2 + 1]) + bgv);
                gp[mt][0] = pack2(g0, g1);
                gp[mt][1] = pack2(g2, g3);
            }
        }

        // H = uh + (S*R)@Wsh + bh ; out = (1-G)*H + Z*S
        zeroacc(acc);
        gemm32(xtb, Wh, lane, acc);
        __syncthreads();   // all waves done reading sb/xtb for this layer
        bool lastl = (l == lcount - 1);
        {
            u32x4 uq = *(const u32x4*)(ub + 3 * 4096 + tid * 8);   // uh
            #pragma unroll
            for (int mt = 0; mt < 2; ++mt) {
                float h0 = acc[mt][0] + bf_lo(uq[mt * 2]) + bhv;
                float h1 = acc[mt][1] + bf_hi(uq[mt * 2]) + bhv;
                float h2 = acc[mt][2] + bf_lo(uq[mt * 2 + 1]) + bhv;
                float h3 = acc[mt][3] + bf_hi(uq[mt * 2 + 1]) + bhv;
                float o0 = bf_lo(gp[mt][0]) * h0 + bf_lo(tp[mt][0]);
                float o1 = bf_hi(gp[mt][0]) * h1 + bf_hi(tp[mt][0]);
                float o2 = bf_lo(gp[mt][1]) * h2 + bf_lo(tp[mt][1]);
                float o3 = bf_hi(gp[mt][1]) * h3 + bf_hi(tp[mt][1]);
                acc[mt] = (f32x4){o0, o1, o2, o3};   // keep for final GEMV
                unsigned p01 = pack2(o0, o1), p23 = pack2(o2, o3);
                sreg[mt][0] = p01; sreg[mt][1] = p23;
                if (!lastl) {
                    int base = mt * 2048 + sc;
                    sb[base + 0]  = (unsigned short)p01;
                    sb[base + 8]  = (unsigned short)(p01 >> 16);
                    sb[base + 16] = (unsigned short)p23;
                    sb[base + 24] = (unsigned short)(p23 >> 16);
                }
            }
        }
        if (!lastl) __syncthreads();   // new S visible for next layer
    }

    // ---- final: y = out @ Wf + Wf_b (per-wave partials, combine via LDS) ----
    float* yp = (float*)xtb;   // safe: barrier after H-gemm ended all xtb reads
    float wfv = Wf_w[col];
    #pragma unroll
    for (int mt = 0; mt < 2; ++mt)
        #pragma unroll
        for (int e = 0; e < 4; ++e) {
            float p = acc[mt][e] * wfv;
            p += __shfl_xor(p, 1);
            p += __shfl_xor(p, 2);
            p += __shfl_xor(p, 4);
            p += __shfl_xor(p, 8);
            if (l15 == 0) yp[(mt * 16 + quad * 4 + e) * 8 + wv] = p;
        }
    __syncthreads();
    if (tid < BROWS) {
        const float* r8 = yp + tid * 8;
        float r = ((r8[0] + r8[1]) + (r8[2] + r8[3])) +
                  ((r8[4] + r8[5]) + (r8[6] + r8[7])) + Wf_b[0];
        y[(size_t)blk * BROWS + tid] = r;
    }
}

extern "C" void kernel_launch(void* const* d_in, const int* in_sizes, int n_in,
                              void* d_out, int out_size, void* d_ws, size_t ws_size,
                              hipStream_t stream) {
    const float* x     = (const float*)d_in[0];
    const float* t     = (const float*)d_in[1];
    const float* Sw_w  = (const float*)d_in[2];
    const float* Sw_b  = (const float*)d_in[3];
    const float* Uz_w  = (const float*)d_in[4];
    const float* Uz_b  = (const float*)d_in[5];
    const float* Wsz_w = (const float*)d_in[6];
    const float* Wsz_b = (const float*)d_in[7];
    const float* Ug_w  = (const float*)d_in[8];
    const float* Ug_b  = (const float*)d_in[9];
    const float* Wsg_w = (const float*)d_in[10];
    const float* Wsg_b = (const float*)d_in[11];
    const float* Ur_w  = (const float*)d_in[12];
    const float* Ur_b  = (const float*)d_in[13];
    const float* Wsr_w = (const float*)d_in[14];
    const float* Wsr_b = (const float*)d_in[15];
    const float* Uh_w  = (const float*)d_in[16];
    const float* Uh_b  = (const float*)d_in[17];
    const float* Wsh_w = (const float*)d_in[18];
    const float* Wsh_b = (const float*)d_in[19];
    const float* Wf_w  = (const float*)d_in[20];
    const float* Wf_b  = (const float*)d_in[21];
    const int*   nl    = (const int*)d_in[22];

    unsigned short* wbuf = (unsigned short*)d_ws;
    float* y = (float*)d_out;
    const int B = in_sizes[0] / XD;

    prep_kernel<<<dim3((NMAT * 2048 + 255) / 256), dim3(256), 0, stream>>>(
        Sw_w, Uz_w, Ug_w, Ur_w, Uh_w, Wsz_w, Wsg_w, Wsr_w, Wsh_w, wbuf);

    dgm_main<<<dim3(B / BROWS), dim3(512), 0, stream>>>(
        x, t, wbuf, Sw_b, Uz_b, Ug_b, Ur_b, Uh_b,
        Wsz_b, Wsg_b, Wsr_b, Wsh_b, Wf_w, Wf_b, nl, y);
}